// Round 8
// baseline (157.999 us; speedup 1.0000x reference)
//
#include <hip/hip_runtime.h>

typedef __attribute__((ext_vector_type(8))) short short8;
typedef __attribute__((ext_vector_type(4))) short short4v;
typedef __attribute__((ext_vector_type(4))) float float4v;

typedef const void __attribute__((address_space(1)))* gptr_t;
typedef void __attribute__((address_space(3)))* lptr_t;

__device__ __forceinline__ void gload_lds16(const void* g, void* l) {
    __builtin_amdgcn_global_load_lds((gptr_t)g, (lptr_t)l, 16, 0, 0);
}

__device__ __forceinline__ unsigned short f2bf(float f) {
    union { float f; unsigned int u; } v; v.f = f;
    unsigned int r = v.u + 0x7fffu + ((v.u >> 16) & 1u);
    return (unsigned short)(r >> 16);
}

__device__ __forceinline__ short8 frag_ld(const unsigned char* base, int row, int k2) {
    return *(const short8*)(base + row * 128 + (k2 ^ ((row & 7) << 4)));
}

__device__ __forceinline__ float4v mfma_bf16(short8 a, short8 b, float4v c) {
    return __builtin_amdgcn_mfma_f32_16x16x32_bf16(a, b, c, 0, 0, 0);
}

// out[a][b] = bf16(in[b][a]), 1024x1024. Also zeroes the 128B zerobuf.
__global__ __launch_bounds__(256) void k_transpose_bf16(
        const float* __restrict__ in, unsigned short* __restrict__ out,
        float* __restrict__ zb) {
    __shared__ float tile[32][33];
    int tx = threadIdx.x, ty = threadIdx.y;
    if (blockIdx.x == 0 && blockIdx.y == 0 && ty == 0) zb[tx] = 0.0f;
    int x = blockIdx.x * 32 + tx;
    int ybase = blockIdx.y * 32;
#pragma unroll
    for (int j = 0; j < 4; j++)
        tile[ty + j * 8][tx] = in[(size_t)(ybase + ty + j * 8) * 1024 + x];
    __syncthreads();
    int ox = ybase + tx;
    int oybase = blockIdx.x * 32;
#pragma unroll
    for (int j = 0; j < 4; j++)
        out[(size_t)(oybase + ty + j * 8) * 1024 + ox] = f2bf(tile[tx][ty + j * 8]);
}

// Pre-pack conv_w into bf16 step-tiles: Bprep[(sl*32+nt)*16+step] = 16KB tile
// [128 n][64 k] row-major bf16. All global streams contiguous; LDS transpose.
__global__ __launch_bounds__(256) void k_prep_B(
        const float* __restrict__ convw,          // [9216][4096]
        unsigned short* __restrict__ Bprep, int sBase) {
    __shared__ float ldsF[64][129];               // pad 129 -> conflict-light
    const int t = threadIdx.x;
    const int p = blockIdx.x;
    const int step = p & 15;
    const int nt   = (p >> 4) & 31;
    const int sl   = p >> 9;
    const int kglob = (sBase + sl) * 1024 + step * 64;

    // read [64 k][128 n] f32: per wave-instr 2 rows x 512B contiguous
    float4v rf[8];
#pragma unroll
    for (int j = 0; j < 8; j++) {
        int r = j * 8 + (t >> 5);
        int c4 = (t & 31) * 4;
        rf[j] = *(const float4v*)(convw + (size_t)(kglob + r) * 4096 + nt * 128 + c4);
    }
#pragma unroll
    for (int j = 0; j < 8; j++) {
        int r = j * 8 + (t >> 5);
        int c4 = (t & 31) * 4;
#pragma unroll
        for (int i = 0; i < 4; i++)
            ldsF[r][c4 + i] = rf[j][i];
    }
    __syncthreads();

    // gather columns, convert, store contiguous 16B chunks
    unsigned short* tile = Bprep + ((size_t)(sl * 32 + nt) * 16 + step) * 8192;
#pragma unroll
    for (int i = 0; i < 4; i++) {
        int q = i * 256 + t;
        int n = q >> 3, c8 = q & 7;
        short8 o;
#pragma unroll
        for (int kk = 0; kk < 8; kk++)
            o[kk] = (short)f2bf(ldsF[8 * c8 + kk][n]);
        *(short8*)(tile + (size_t)q * 8) = o;
    }
}

// conv-as-GEMM: tile M=128 x N=128; A via gload_lds double-buffer; B consumed
// DIRECTLY from Bprep step-tiles (per-frag 2KB-contiguous global loads, L3-hot).
// No ldsB, no f2bf in loop. Plain stores to y_part (mt rows disjoint).
__global__ __launch_bounds__(256, 3) void k_conv_gemm(
        const unsigned short* __restrict__ peT,   // [1024][1024] bf16
        const unsigned short* __restrict__ zerobuf,
        const unsigned short* __restrict__ Bprep,
        float* __restrict__ y_part, int sBase)    // [9][256][4096]
{
    __shared__ __align__(16) unsigned char ldsA[2][16384]; // [128 m][64 k] bf16

    const int t = threadIdx.x;
    const int L = blockIdx.x;
    const int cpx = gridDim.x >> 3;               // bijective XCD chunking (nwg%8==0)
    const int ell = (L & 7) * cpx + (L >> 3);
    const int mt = ell & 1;
    const int nt = (ell >> 1) & 31;
    const int sl = ell >> 6;
    const int s  = sBase + sl;
    const int kh = s / 3, kw = s - kh * 3;
    const int ncol0 = nt * 128;

    const int l = t & 63, w = t >> 6;
    const int wm = w >> 1, wn = w & 1;            // wave tile 64m x 64n
    const int l15 = l & 15;
    const int lk2 = (l >> 4) * 16;

    float4v acc[4][4] = {};

    // A staging sources: 4 x 16B chunks per thread, pre-swizzled global source
    const unsigned short* asrc[4];
    int aok[4];
#pragma unroll
    for (int i = 0; i < 4; i++) {
        int idx = i * 256 + t;
        int r = idx >> 3, c8 = idx & 7;
        int m = mt * 128 + r;
        int oh = m >> 4, ow = m & 15;
        int ih = 2 * oh + kh, iw = 2 * ow + kw;
        bool ok = (ih < 32) && (iw < 32);
        asrc[i] = ok ? (peT + (size_t)(ih * 32 + iw) * 1024 + ((c8 ^ (r & 7)) * 8))
                     : zerobuf;
        aok[i] = ok ? ~0 : 0;
    }

    const unsigned char* Bt = (const unsigned char*)Bprep
                            + (size_t)((sl * 32 + nt) * 16) * 16384;

    // ---- prologue: issue A(0), A(1); land A(0) ----
#pragma unroll
    for (int i = 0; i < 4; i++)
        gload_lds16(asrc[i], &ldsA[0][(i * 256 + t) * 16]);
    __builtin_amdgcn_sched_barrier(0);
#pragma unroll
    for (int i = 0; i < 4; i++)
        gload_lds16(asrc[i] + (64 & aok[i]), &ldsA[1][(i * 256 + t) * 16]);
    asm volatile("s_waitcnt vmcnt(4)" ::: "memory");
    __builtin_amdgcn_sched_barrier(0);
    __builtin_amdgcn_s_barrier();                 // tile 0 in LDS

    // ---- main loop: 16 K-steps, fully unrolled ----
#pragma unroll
    for (int tt = 0; tt < 16; ++tt) {
        const int cur = tt & 1;

        // B frags direct from global step-tile (8 x 16B, 2KB-contiguous per instr)
        const unsigned char* tileT = Bt + tt * 16384;
        short8 bfr[4][2];
#pragma unroll
        for (int nf = 0; nf < 4; nf++)
#pragma unroll
            for (int ks = 0; ks < 2; ks++)
                bfr[nf][ks] = *(const short8*)(tileT
                    + (wn * 64 + nf * 16 + l15) * 128 + (ks * 64 + lk2));
        __builtin_amdgcn_sched_barrier(0);

        // A frags from LDS
        short8 af[4][2];
#pragma unroll
        for (int mf = 0; mf < 4; mf++)
#pragma unroll
            for (int ks = 0; ks < 2; ks++)
                af[mf][ks] = frag_ld(ldsA[cur], wm * 64 + mf * 16 + l15, ks * 64 + lk2);
        asm volatile("s_waitcnt lgkmcnt(0)" ::: "memory");
        __builtin_amdgcn_sched_barrier(0);
        __builtin_amdgcn_s_barrier();             // all waves done reading ldsA[cur]
        __builtin_amdgcn_sched_barrier(0);

        // issue A(tt+2) into ldsA[cur]
        if (tt < 14) {
            const int k0n = (tt + 2) * 64;
#pragma unroll
            for (int i = 0; i < 4; i++)
                gload_lds16(asrc[i] + (k0n & aok[i]), &ldsA[cur][(i * 256 + t) * 16]);
        }
        __builtin_amdgcn_sched_barrier(0);
        // land A(tt+1) + B(tt); leave A(tt+2) in flight
        if (tt < 14) asm volatile("s_waitcnt vmcnt(4)" ::: "memory");
        else         asm volatile("s_waitcnt vmcnt(0)" ::: "memory");
        __builtin_amdgcn_sched_barrier(0);

        __builtin_amdgcn_s_setprio(1);
#pragma unroll
        for (int mf = 0; mf < 4; mf++)
#pragma unroll
            for (int nf = 0; nf < 4; nf++)
#pragma unroll
                for (int ks = 0; ks < 2; ks++)
                    acc[mf][nf] = mfma_bf16(af[mf][ks], bfr[nf][ks], acc[mf][nf]);
        __builtin_amdgcn_s_setprio(0);

        if (tt < 15) __builtin_amdgcn_s_barrier();  // A(tt+1) visible to all waves
    }

    // epilogue: plain stores into this slice's partial buffer
    float* yp = y_part + (size_t)s * 1048576;
#pragma unroll
    for (int mf = 0; mf < 4; mf++) {
        int row = mt * 128 + wm * 64 + mf * 16 + (l >> 4) * 4;
#pragma unroll
        for (int nf = 0; nf < 4; nf++) {
            int col = ncol0 + wn * 64 + nf * 16 + l15;
#pragma unroll
            for (int rr = 0; rr < 4; rr++)
                yp[(size_t)(row + rr) * 4096 + col] = acc[mf][nf][rr];
        }
    }
}

// sum 9 slice partials + bias, BN (moving stats) + LeakyReLU, scatter to pos2img[y][x]
__global__ __launch_bounds__(256) void k_bn_pos2(
        const float* __restrict__ y_part, const float* __restrict__ cb,
        const float* __restrict__ gamma, const float* __restrict__ beta,
        const float* __restrict__ mean, const float* __restrict__ var,
        float* __restrict__ pos2img) {
    int idx = blockIdx.x * 256 + threadIdx.x;   // [m=256][oc=4096]
    int m = idx >> 12, oc = idx & 4095;
    float v = cb[oc];
#pragma unroll
    for (int s = 0; s < 9; s++)
        v += y_part[(size_t)s * 1048576 + idx];
    v = (v - mean[oc]) * (gamma[oc] * rsqrtf(var[oc] + 1e-3f)) + beta[oc];
    v = v > 0.0f ? v : 0.3f * v;
    int y = ((oc >> 6) << 4) + (m >> 4);
    int x = ((oc & 63) << 4) + (m & 15);
    pos2img[y * 1024 + x] = v;
}

// enc0[b,n0,d0] = X[b,y,x] + pos2img[y,x] + W_emb[n0,d0], cast bf16
__global__ __launch_bounds__(256) void k_build_A(
        const float* __restrict__ X, const float* __restrict__ pos2img,
        const float* __restrict__ W_emb, unsigned short* __restrict__ Aenc) {
    int row = blockIdx.x;            // b*1024 + n0
    int n0 = row & 1023;
    int b  = row >> 10;
    int d0 = threadIdx.x * 4;
    int y = ((n0 >> 5) << 5) + (d0 >> 5);
    int x = ((n0 & 31) << 5) + (d0 & 31);
    size_t pix = (size_t)y * 1024 + x;
    float4v xv = *(const float4v*)(X + (size_t)b * 1048576 + pix);
    float4v pv = *(const float4v*)(pos2img + pix);
    float4v wv = *(const float4v*)(W_emb + (size_t)n0 * 1024 + d0);
    short4v o;
    o.x = (short)f2bf(xv.x + pv.x + wv.x);
    o.y = (short)f2bf(xv.y + pv.y + wv.y);
    o.z = (short)f2bf(xv.z + pv.z + wv.z);
    o.w = (short)f2bf(xv.w + pv.w + wv.w);
    *(short4v*)(Aenc + (size_t)row * 1024 + d0) = o;
}

// C[8192][1024] = A[8192][1024] * W_dense[1024][1024] + bias, bf16 MFMA
__global__ __launch_bounds__(256) void k_final_gemm(
        const unsigned short* __restrict__ A,   // [8192][1024] bf16
        const unsigned short* __restrict__ Bt,  // [1024][1024] bf16 = W_dense^T
        const float* __restrict__ bias,
        float* __restrict__ C) {
    __shared__ __align__(16) unsigned char ldsA[16384];
    __shared__ __align__(16) unsigned char ldsB[16384];
    const int t = threadIdx.x;
    const int L = blockIdx.x;
    const int ell = (L & 7) * 64 + (L >> 3);
    const int col0 = (ell & 7) * 128;
    const int row0 = (ell >> 3) * 128;
    const int l = t & 63, w = t >> 6;
    const int wm = w >> 1, wn = w & 1;
    const int l15 = l & 15;
    const int lk2 = (l >> 4) * 16;

    float4v acc[4][4] = {};

    const unsigned short* asrc[4];
    const unsigned short* bsrc[4];
#pragma unroll
    for (int i = 0; i < 4; i++) {
        int idx = i * 256 + t;
        int r = idx >> 3, c8 = idx & 7;
        int cofs = (c8 ^ (r & 7)) * 8;
        asrc[i] = A  + (size_t)(row0 + r) * 1024 + cofs;
        bsrc[i] = Bt + (size_t)(col0 + r) * 1024 + cofs;
    }

    for (int k0 = 0; k0 < 1024; k0 += 64) {
#pragma unroll
        for (int i = 0; i < 4; i++) {
            int idx = i * 256 + t;
            gload_lds16(asrc[i] + k0, ldsA + idx * 16);
            gload_lds16(bsrc[i] + k0, ldsB + idx * 16);
        }
        __syncthreads();

        short8 af[4][2], bfr[4][2];
#pragma unroll
        for (int mf = 0; mf < 4; mf++)
#pragma unroll
            for (int ks = 0; ks < 2; ks++)
                af[mf][ks] = frag_ld(ldsA, wm * 64 + mf * 16 + l15, ks * 64 + lk2);
#pragma unroll
        for (int nf = 0; nf < 4; nf++)
#pragma unroll
            for (int ks = 0; ks < 2; ks++)
                bfr[nf][ks] = frag_ld(ldsB, wn * 64 + nf * 16 + l15, ks * 64 + lk2);
#pragma unroll
        for (int mf = 0; mf < 4; mf++)
#pragma unroll
            for (int nf = 0; nf < 4; nf++)
#pragma unroll
                for (int ks = 0; ks < 2; ks++)
                    acc[mf][nf] = mfma_bf16(af[mf][ks], bfr[nf][ks], acc[mf][nf]);
        __syncthreads();
    }

#pragma unroll
    for (int nf = 0; nf < 4; nf++) {
        int col = col0 + wn * 64 + nf * 16 + l15;
        float bv = bias[col];
#pragma unroll
        for (int mf = 0; mf < 4; mf++) {
            int row = row0 + wm * 64 + mf * 16 + (l >> 4) * 4;
#pragma unroll
            for (int r = 0; r < 4; r++)
                C[(size_t)(row + r) * 1024 + col] = acc[mf][nf][r] + bv;
        }
    }
}

extern "C" void kernel_launch(void* const* d_in, const int* in_sizes, int n_in,
                              void* d_out, int out_size, void* d_ws, size_t ws_size,
                              hipStream_t stream) {
    (void)in_sizes; (void)n_in; (void)out_size;
    const float* X       = (const float*)d_in[0];
    const float* W_emb   = (const float*)d_in[1];
    const float* conv_w  = (const float*)d_in[2];
    const float* conv_b  = (const float*)d_in[3];
    const float* gamma   = (const float*)d_in[4];
    const float* beta    = (const float*)d_in[5];
    const float* mean    = (const float*)d_in[6];
    const float* var     = (const float*)d_in[7];
    const float* W_dense = (const float*)d_in[8];
    const float* b_dense = (const float*)d_in[9];
    float* out = (float*)d_out;

    const size_t MB = 1u << 20;
    unsigned char* ws = (unsigned char*)d_ws;
    float*          y_part  = (float*)(ws);                 // [0,36) MB
    float*          zerobuf = (float*)(ws + 36 * MB);       // 4 KB
    unsigned short* peT     = (unsigned short*)(ws + 37 * MB); // 2 MB
    unsigned short* Bprep   = (unsigned short*)(ws + 39 * MB); // 24 or 72 MB
    // overlays (used only after all convs complete):
    float*          pos2img = (float*)(ws + 39 * MB);       // 4 MB
    unsigned short* Aenc    = (unsigned short*)(ws + 43 * MB); // 16 MB
    unsigned short* WdT     = (unsigned short*)(ws + 59 * MB); // 2 MB

    // Path A (single prep+conv, full chip) needs 39+72=111 MB of workspace.
    const int nCh    = (ws_size >= 112 * MB) ? 1 : 3;
    const int sCount = (nCh == 1) ? 9 : 3;

    dim3 tb(32, 8);
    k_transpose_bf16<<<dim3(32, 32), tb, 0, stream>>>(W_emb, peT, zerobuf);
    for (int c = 0; c < nCh; c++) {
        int sBase = c * sCount;
        k_prep_B<<<sCount * 512, 256, 0, stream>>>(conv_w, Bprep, sBase);
        k_conv_gemm<<<sCount * 64, 256, 0, stream>>>(
            peT, (const unsigned short*)zerobuf, Bprep, y_part, sBase);
    }
    k_bn_pos2<<<4096, 256, 0, stream>>>(y_part, conv_b, gamma, beta, mean, var, pos2img);
    k_build_A<<<8192, 256, 0, stream>>>(X, pos2img, W_emb, Aenc);
    k_transpose_bf16<<<dim3(32, 32), tb, 0, stream>>>(W_dense, WdT, zerobuf);
    k_final_gemm<<<512, 256, 0, stream>>>(Aenc, WdT, b_dense, out);
}